// Round 14
// baseline (250.765 us; speedup 1.0000x reference)
//
#include <hip/hip_runtime.h>

typedef unsigned int uint;
typedef unsigned short ushort;
typedef __attribute__((ext_vector_type(8))) short short8;
typedef __attribute__((ext_vector_type(4))) float f32x4;

__device__ __forceinline__ float b2f(ushort u) {
    return __uint_as_float(((uint)u) << 16);
}
__device__ __forceinline__ ushort f2b(float f) {
    uint u = __float_as_uint(f);
    u += 0x7FFFu + ((u >> 16) & 1u);   // round-to-nearest-even
    return (ushort)(u >> 16);
}
__device__ __forceinline__ float fast_exp2(float v) {
    float r;
    asm volatile("v_exp_f32 %0, %1" : "=v"(r) : "v"(v));   // D = 2^S0
    return r;
}

template<int CTRL>
__device__ __forceinline__ float dpp_add(float v) {
    int s = __float_as_int(v);
    int d = __builtin_amdgcn_update_dpp(s, s, CTRL, 0xF, 0xF, true);
    return v + __int_as_float(d);
}

// ---------------------------------------------------------------------------
// GEMM: xs = x @ Wsrc + bsrc (bf16 out) ; xd = x @ Wdst + bdst (f32 out)
// ---------------------------------------------------------------------------
#define LDW 136

__global__ __launch_bounds__(512) void gemm_kernel(
    const float* __restrict__ x,
    const float* __restrict__ Wsrc, const float* __restrict__ bsrc,
    const float* __restrict__ Wdst, const float* __restrict__ bdst,
    ushort* __restrict__ xs, float* __restrict__ xd, int n)
{
    __shared__ ushort WtS[128 * LDW];
    __shared__ ushort WtD[128 * LDW];
    int t = threadIdx.x;
    for (int i = t * 4; i < 128 * 128; i += 512 * 4) {
        int k = i >> 7, c = i & 127;
        float4 wS = *(const float4*)(Wsrc + i);
        float4 wD = *(const float4*)(Wdst + i);
        WtS[(c + 0) * LDW + k] = f2b(wS.x);
        WtS[(c + 1) * LDW + k] = f2b(wS.y);
        WtS[(c + 2) * LDW + k] = f2b(wS.z);
        WtS[(c + 3) * LDW + k] = f2b(wS.w);
        WtD[(c + 0) * LDW + k] = f2b(wD.x);
        WtD[(c + 1) * LDW + k] = f2b(wD.y);
        WtD[(c + 2) * LDW + k] = f2b(wD.z);
        WtD[(c + 3) * LDW + k] = f2b(wD.w);
    }
    __syncthreads();

    int wave = t >> 6, lane = t & 63;
    int r = lane & 15, q = lane >> 4;
    int row = blockIdx.x * 128 + wave * 16 + r;
    f32x4 accS[8], accD[8];
#pragma unroll
    for (int i = 0; i < 8; i++) { accS[i] = (f32x4)(0.f); accD[i] = (f32x4)(0.f); }

#pragma unroll
    for (int kk = 0; kk < 4; kk++) {
        float v[8];
#pragma unroll
        for (int j = 0; j < 8; j++) v[j] = 0.f;
        if (row < n) {
            const float4* src = (const float4*)(x + (size_t)row * 128 + kk * 32 + q * 8);
            float4 p0 = src[0], p1 = src[1];
            v[0] = p0.x; v[1] = p0.y; v[2] = p0.z; v[3] = p0.w;
            v[4] = p1.x; v[5] = p1.y; v[6] = p1.z; v[7] = p1.w;
        }
        short8 ah, al;
#pragma unroll
        for (int j = 0; j < 8; j++) {
            ushort h = f2b(v[j]);
            ah[j] = (short)h;
            al[j] = (short)f2b(v[j] - b2f(h));
        }
#pragma unroll
        for (int ct = 0; ct < 8; ct++) {
            int off = (ct * 16 + r) * LDW + kk * 32 + q * 8;
            short8 bS = *(const short8*)(WtS + off);
            short8 bD = *(const short8*)(WtD + off);
            accS[ct] = __builtin_amdgcn_mfma_f32_16x16x32_bf16(ah, bS, accS[ct], 0, 0, 0);
            accS[ct] = __builtin_amdgcn_mfma_f32_16x16x32_bf16(al, bS, accS[ct], 0, 0, 0);
            accD[ct] = __builtin_amdgcn_mfma_f32_16x16x32_bf16(ah, bD, accD[ct], 0, 0, 0);
            accD[ct] = __builtin_amdgcn_mfma_f32_16x16x32_bf16(al, bD, accD[ct], 0, 0, 0);
        }
    }
    int rbase = blockIdx.x * 128 + wave * 16 + q * 4;
#pragma unroll
    for (int ct = 0; ct < 8; ct++) {
        int col = ct * 16 + r;
        float bS = bsrc[col];
        float bD = bdst[col];
#pragma unroll
        for (int rg = 0; rg < 4; rg++) {
            int orow = rbase + rg;
            if (orow < n) {
                xs[(size_t)orow * 128 + col] = f2b(accS[ct][rg] + bS);
                xd[(size_t)orow * 128 + col] = accD[ct][rg] + bD;
            }
        }
    }
}

// ---------------------------------------------------------------------------
// Fused CSR build: count -> scan -> fill in ONE kernel with grid barriers.
// 128 blocks x 256 thr (<= 256 CUs => all co-resident => spin barrier safe).
// Cross-block payload via device-scope atomics (atomicExch write / add-0 read)
// to sidestep XCD L2 non-coherence; __threadfence for release/acquire.
// deg and bar[4] pre-zeroed by hipMemsetAsync. esrc padded with 64 zeros.
// ---------------------------------------------------------------------------
#define CSRB 128
#define CSRT 256

__device__ __forceinline__ void gbar(int* ctr, int target) {
    __syncthreads();
    if (threadIdx.x == 0) {
        __threadfence();
        atomicAdd(ctr, 1);
        while (atomicAdd(ctr, 0) < target) {}
        __threadfence();
    }
    __syncthreads();
}

__global__ __launch_bounds__(CSRT) void csr_kernel(
    const int* __restrict__ ei, int E, int n,
    int* __restrict__ deg, int* __restrict__ row_start,
    int* __restrict__ cursor, int* __restrict__ esrc,
    int* __restrict__ bsum, int* __restrict__ bpre, int* __restrict__ bar)
{
    int t = threadIdx.x, b = blockIdx.x;
    int lane = t & 63, w = t >> 6;
    __shared__ int f_s;
    __shared__ int ws[4], wp[4];
    if (t < 64) {
        int wv = ei[2 * t + 1];
        unsigned long long nz = __ballot(wv != 0);
        if (t == 0) f_s = (nz == 0ULL) ? 1 : 0;   // 1 = int64 edges
    }
    __syncthreads();
    int f = f_s;
    const int NT = CSRB * CSRT;
    int g = b * CSRT + t;

    // ---- P1: degree count (excluding self-loops; scan adds +1)
    if (f) {
        int half = E >> 1;
        const uint4* dp = ((const uint4*)ei) + (E >> 1);   // dst int64 pairs
        for (int i = g; i < half; i += NT) {
            uint4 dq = dp[i];
            atomicAdd(&deg[(int)dq.x], 1);
            atomicAdd(&deg[(int)dq.z], 1);
        }
        if ((E & 1) && g == 0) atomicAdd(&deg[ei[2 * E + 2 * (E - 1)]], 1);
    } else {
        for (int e = g; e < E; e += NT) atomicAdd(&deg[ei[E + e]], 1);
    }
    gbar(&bar[0], CSRB);

    // ---- P2a: block-local scan (2 elems/thread), self-loop +1 folded in
    const int C = (n + CSRB - 1) / CSRB;
    int lo = b * C;
    int hi = min(lo + C, n);
    int i0 = lo + 2 * t, i1 = i0 + 1;
    int d0 = (i0 < hi) ? deg[i0] + 1 : 0;
    int d1 = (i1 < hi) ? deg[i1] + 1 : 0;
    int s2 = d0 + d1;
    int inc = s2;
#pragma unroll
    for (int off = 1; off < 64; off <<= 1) {
        int sh = __shfl_up(inc, off);
        if (lane >= off) inc += sh;
    }
    if (lane == 63) ws[w] = inc;
    __syncthreads();
    if (t == 0) {
        int run = 0;
#pragma unroll
        for (int i = 0; i < 4; i++) { wp[i] = run; run += ws[i]; }
        atomicExch(&bsum[b], run);
    }
    __syncthreads();
    int excl = wp[w] + inc - s2;
    gbar(&bar[1], CSRB);

    // ---- P2b: block 0 scans the 128 block sums
    if (b == 0) {
        int v = (t < CSRB) ? atomicAdd(&bsum[t], 0) : 0;
        int inc2 = v;
#pragma unroll
        for (int off = 1; off < 64; off <<= 1) {
            int sh = __shfl_up(inc2, off);
            if (lane >= off) inc2 += sh;
        }
        if (lane == 63) ws[w] = inc2;
        __syncthreads();
        if (t == 0) {
            int run = 0;
#pragma unroll
            for (int i = 0; i < 4; i++) { wp[i] = run; run += ws[i]; }
            row_start[n] = run;                 // grand total (read next dispatch)
        }
        __syncthreads();
        int ex2 = wp[w] + inc2 - v;
        if (t < CSRB) atomicExch(&bpre[t], ex2);
    }
    gbar(&bar[2], CSRB);

    // ---- P2c: emit row_start + cursor
    int boff = atomicAdd(&bpre[b], 0);
    if (i0 < hi) { int rs = boff + excl;      row_start[i0] = rs; atomicExch(&cursor[i0], rs); }
    if (i1 < hi) { int rs = boff + excl + d0; row_start[i1] = rs; atomicExch(&cursor[i1], rs); }
    gbar(&bar[3], CSRB);

    // ---- P3: fill edge lists + self-loops + zero pad
    if (f) {
        int half = E >> 1;
        const uint4* sp = (const uint4*)ei;
        const uint4* dp = sp + (E >> 1);
        for (int i = g; i < half; i += NT) {
            uint4 sq = sp[i], dq = dp[i];
            int p0 = atomicAdd(&cursor[(int)dq.x], 1); esrc[p0] = (int)sq.x;
            int p1 = atomicAdd(&cursor[(int)dq.z], 1); esrc[p1] = (int)sq.z;
        }
        if ((E & 1) && g == 0) {
            int e = E - 1;
            int p0 = atomicAdd(&cursor[ei[2 * E + 2 * e]], 1);
            esrc[p0] = ei[2 * e];
        }
    } else {
        for (int e = g; e < E; e += NT) {
            int p0 = atomicAdd(&cursor[ei[E + e]], 1);
            esrc[p0] = ei[e];
        }
    }
    for (int i = g; i < n; i += NT) {
        int p0 = atomicAdd(&cursor[i], 1);
        esrc[p0] = i;                            // self-loop
    }
    if (g < 64) esrc[E + n + g] = 0;             // pad for unclamped prefetch
}

// ---------------------------------------------------------------------------
// Fused node kernel: 1 wave = 1 node, 4 edges/iter. Quarter q -> edge base+q;
// lane r owns channels [8r, 8r+8). leaky via 0.6t+0.4|t| identity, exp2 domain.
// ---------------------------------------------------------------------------
__global__ __launch_bounds__(64, 4) void node_kernel(
    const ushort* __restrict__ xs, const float* __restrict__ xd,
    const float* __restrict__ x,  const float* __restrict__ att,
    const float* __restrict__ bias_out, const float* __restrict__ gamma,
    const float* __restrict__ beta,
    const int* __restrict__ row_start, const int* __restrict__ esrc,
    float* __restrict__ out, int n)
{
    int lane = threadIdx.x;
    int node = blockIdx.x;
    if (node >= n) return;
    int q = lane >> 4, r = lane & 15;
    int cb = r * 8;

    const float LOG2E = 1.44269504088896f;
    const float A = 0.6f * LOG2E, B = 0.4f * LOG2E;

    float xdc[8], atc[8];
    {
        const float4* xp = (const float4*)(xd + (size_t)node * 128 + cb);
        float4 p0 = xp[0], p1 = xp[1];
        xdc[0]=p0.x; xdc[1]=p0.y; xdc[2]=p0.z; xdc[3]=p0.w;
        xdc[4]=p1.x; xdc[5]=p1.y; xdc[6]=p1.z; xdc[7]=p1.w;
        const float4* ap = (const float4*)(att + cb);
        float4 a0 = ap[0], a1 = ap[1];
        atc[0]=a0.x; atc[1]=a0.y; atc[2]=a0.z; atc[3]=a0.w;
        atc[4]=a1.x; atc[5]=a1.y; atc[6]=a1.z; atc[7]=a1.w;
    }
    float KL = 0.f;
#pragma unroll
    for (int i = 0; i < 8; i++) KL = fmaf(atc[i], xdc[i], KL);
    KL *= A;

    int start = row_start[node], end = row_start[node + 1];
    float s = 0.f, acc[8];
#pragma unroll
    for (int i = 0; i < 8; i++) acc[i] = 0.f;

    uint cboff = (uint)cb;
    int j0 = esrc[start + q];                    // padded esrc: always in-bounds
    uint4 raw = *(const uint4*)(xs + (uint)j0 * 128u + cboff);

    for (int base = start; base < end; base += 4) {
        int jn = esrc[base + 4 + q];
        uint4 rawn = *(const uint4*)(xs + (uint)jn * 128u + cboff);   // prefetch

        float v[8];
        v[0] = __uint_as_float(raw.x << 16); v[1] = __uint_as_float(raw.x & 0xFFFF0000u);
        v[2] = __uint_as_float(raw.y << 16); v[3] = __uint_as_float(raw.y & 0xFFFF0000u);
        v[4] = __uint_as_float(raw.z << 16); v[5] = __uint_as_float(raw.z & 0xFFFF0000u);
        v[6] = __uint_as_float(raw.w << 16); v[7] = __uint_as_float(raw.w & 0xFFFF0000u);

        float dv = 0.f, da = 0.f;
#pragma unroll
        for (int i = 0; i < 8; i++) {
            dv = fmaf(atc[i], v[i], dv);                   // att . v
            da = fmaf(atc[i], fabsf(v[i] + xdc[i]), da);   // att . |v+xd|
        }
        float P = fmaf(A, dv, fmaf(B, da, KL));
        P = dpp_add<0xB1>(P);                // pair sum -> head logit (log2 dom)
        float p = fast_exp2(P);
        p = (base + q < end) ? p : 0.f;      // mask tail dups
        s += p;
#pragma unroll
        for (int i = 0; i < 8; i++) acc[i] = fmaf(p, v[i], acc[i]);

        raw = rawn;
    }

#pragma unroll
    for (int off = 16; off <= 32; off <<= 1) {
        s += __shfl_xor(s, off);
#pragma unroll
        for (int i = 0; i < 8; i++) acc[i] += __shfl_xor(acc[i], off);
    }

    float inv = 1.f / s;
    float o[8];
    {
        const float4* bp = (const float4*)(bias_out + cb);
        const float4* xp = (const float4*)(x + (size_t)node * 128 + cb);
        float4 b0 = bp[0], b1 = bp[1], x0 = xp[0], x1 = xp[1];
        o[0] = fmaf(acc[0], inv, b0.x + x0.x); o[1] = fmaf(acc[1], inv, b0.y + x0.y);
        o[2] = fmaf(acc[2], inv, b0.z + x0.z); o[3] = fmaf(acc[3], inv, b0.w + x0.w);
        o[4] = fmaf(acc[4], inv, b1.x + x1.x); o[5] = fmaf(acc[5], inv, b1.y + x1.y);
        o[6] = fmaf(acc[6], inv, b1.z + x1.z); o[7] = fmaf(acc[7], inv, b1.w + x1.w);
    }
    float ssum = 0.f, ssq = 0.f;
#pragma unroll
    for (int i = 0; i < 8; i++) {
        ssum += o[i];
        ssq  = fmaf(o[i], o[i], ssq);
    }
#pragma unroll
    for (int off = 1; off <= 8; off <<= 1) {
        ssum += __shfl_xor(ssum, off);
        ssq  += __shfl_xor(ssq, off);
    }
    float mean = ssum * (1.f / 128.f);
    float var  = ssq  * (1.f / 128.f) - mean * mean;
    float rstd = rsqrtf(var + 1e-5f);

    if (q == 0) {
        const float4* gp = (const float4*)(gamma + cb);
        const float4* ep = (const float4*)(beta + cb);
        float4 g0 = gp[0], g1 = gp[1], e0 = ep[0], e1 = ep[1];
        float gch[8] = {g0.x, g0.y, g0.z, g0.w, g1.x, g1.y, g1.z, g1.w};
        float ech[8] = {e0.x, e0.y, e0.z, e0.w, e1.x, e1.y, e1.z, e1.w};
        float res[8];
#pragma unroll
        for (int i = 0; i < 8; i++) {
            float gg = (o[i] - mean) * rstd * gch[i] + ech[i];
            res[i] = 0.5f * gg * (1.f + erff(gg * 0.70710678118654752f));
        }
        float4* op = (float4*)(out + (size_t)node * 128 + cb);
        float4 r0, r1;
        r0.x = res[0]; r0.y = res[1]; r0.z = res[2]; r0.w = res[3];
        r1.x = res[4]; r1.y = res[5]; r1.z = res[6]; r1.w = res[7];
        op[0] = r0; op[1] = r1;
    }
}

// ---------------------------------------------------------------------------
extern "C" void kernel_launch(void* const* d_in, const int* in_sizes, int n_in,
                              void* d_out, int out_size, void* d_ws, size_t ws_size,
                              hipStream_t stream)
{
    const float* x    = (const float*)d_in[0];
    const int*   ei   = (const int*)d_in[1];
    const float* Wsrc = (const float*)d_in[2];
    const float* bsrc = (const float*)d_in[3];
    const float* Wdst = (const float*)d_in[4];
    const float* bdst = (const float*)d_in[5];
    const float* att  = (const float*)d_in[6];
    const float* bout = (const float*)d_in[7];
    const float* gam  = (const float*)d_in[8];
    const float* bet  = (const float*)d_in[9];
    float* out = (float*)d_out;

    int n = in_sizes[0] / 128;
    int E = in_sizes[1] / 2;

    char* p = (char*)d_ws;
    auto alloc = [&](size_t bytes) {
        char* q = p;
        p += (bytes + 255) & ~((size_t)255);
        return q;
    };
    ushort* xs        = (ushort*)alloc((size_t)n * 128 * 2);
    float*  xd        = (float*)alloc((size_t)n * 128 * 4);
    int*    deg       = (int*)alloc((size_t)(n + 4) * 4);   // deg[n] + bar[4]
    int*    bar       = deg + n;
    int*    row_start = (int*)alloc((size_t)(n + 1) * 4);
    int*    cursor    = (int*)alloc((size_t)n * 4);
    int*    esrc      = (int*)alloc((size_t)(E + n + 64) * 4);
    int*    bsum      = (int*)alloc((size_t)CSRB * 4);
    int*    bpre      = (int*)alloc((size_t)CSRB * 4);

    hipMemsetAsync(deg, 0, (size_t)(n + 4) * 4, stream);    // zero deg + barriers
    hipLaunchKernelGGL(gemm_kernel, dim3((n + 127) / 128), dim3(512), 0, stream,
                       x, Wsrc, bsrc, Wdst, bdst, xs, xd, n);
    hipLaunchKernelGGL(csr_kernel, dim3(CSRB), dim3(CSRT), 0, stream,
                       ei, E, n, deg, row_start, cursor, esrc, bsum, bpre, bar);
    hipLaunchKernelGGL(node_kernel, dim3(n), dim3(64), 0, stream,
                       xs, xd, x, att, bout, gam, bet, row_start, esrc, out, n);
}